// Round 10
// baseline (9765.056 us; speedup 1.0000x reference)
//
#include <hip/hip_runtime.h>

#define Bb 128
#define Tt 512
#define Vv 96
#define Hh 512
#define OUT_H 6291456
#define OUT_C 6488064

typedef _Float16 f16x4 __attribute__((ext_vector_type(4)));
typedef _Float16 f16x8 __attribute__((ext_vector_type(8)));
typedef float f32x4 __attribute__((ext_vector_type(4)));

struct KP {
  const float *x, *h0, *c0;
  const float *Wih0, *Whh0, *bih0, *bhh0;
  const float *Wih1, *Whh1, *bih1, *bhh1;
  const float *Wih2, *Whh2, *bih2, *bhh2;
  const float *Wfc, *bfc;
  float* out;
  unsigned* flags;   // [7 groups][32 words]: 1 cacheline per subgroup, single writer/word
  float* fbias;      // [3][2048] gate biases + [96] fc bias
  _Float16* wimg;    // [96][65536] cell weight images (W_hh | W_ih), pre-swizzled
  _Float16* wfc;     // [49152] FC weight image, pre-swizzled
  _Float16* xb;      // [128][512][96] f16 input
  _Float16* hbuf;    // [6 grp][32 slots][64][512] f16 h ring (write-once per slot/period)
};

__device__ __forceinline__ float sigf(float x) { return 1.f / (1.f + __expf(-x)); }

__device__ __forceinline__ void st_dc_u32(unsigned* p, unsigned v) {
  __hip_atomic_store(p, v, __ATOMIC_RELAXED, __HIP_MEMORY_SCOPE_AGENT);
}

// Dual wait: lane-private (word,target) pairs; backoff after 64 fast polls.
__device__ __forceinline__ void wait2(unsigned* flags, int w1, int t1, int w2, int t2) {
  unsigned* p1 = flags + w1;
  unsigned* p2 = flags + w2;
  int g = 0;
  for (;;) {
    int v1 = (int)__hip_atomic_load(p1, __ATOMIC_RELAXED, __HIP_MEMORY_SCOPE_AGENT);
    int v2 = (int)__hip_atomic_load(p2, __ATOMIC_RELAXED, __HIP_MEMORY_SCOPE_AGENT);
    if (__all(v1 >= t1 && v2 >= t2)) break;
    if (++g > 30000) break;   // deadlock terminates; absmax diagnoses
    if (g < 64) __builtin_amdgcn_s_sleep(2);
    else        __builtin_amdgcn_s_sleep(4);
  }
}

// Load 2 m-frags x KS k-steps of A (plain cached; h slots write-once per period).
template <int KS>
__device__ __forceinline__ void load2(const _Float16* __restrict__ p, f16x4 (&av)[2][KS]) {
#pragma unroll
  for (int m = 0; m < 2; ++m)
#pragma unroll
    for (int i = 0; i < KS; ++i)
      av[m][i] = *(const f16x4*)(p + m * 16 * 512 + i * 16);
}

// acc[2][NF] += av * W^T; B frag read ONCE per (i,n), reused across both m-frags.
// Swizzle (gr&15)<<2 halfwords: provably uniform 4 words/bank for this pattern.
template <int KS, int NF>
__device__ __forceinline__ void mma2(const f16x4 (&av)[2][KS], const _Float16* ldsb,
                                     int kb, int nbase, int l15, int l4,
                                     f32x4 (&acc)[2][NF]) {
#pragma unroll
  for (int i = 0; i < KS; ++i) {
#pragma unroll
    for (int n = 0; n < NF; ++n) {
      const int gr = (nbase + n) * 16 + l15;
      const int idx = ((gr << 9) + kb + i * 16 + (l4 << 2)) ^ ((gr & 15) << 2);
      f16x4 bv = *(const f16x4*)(ldsb + idx);
      acc[0][n] = __builtin_amdgcn_mfma_f32_16x16x16f16(av[0][i], bv, acc[0][n], 0, 0, 0);
      acc[1][n] = __builtin_amdgcn_mfma_f32_16x16x16f16(av[1][i], bv, acc[1][n], 0, 0, 0);
    }
  }
}

__global__ __launch_bounds__(256) void prologue_kernel(KP A) {
  const int tid = threadIdx.x, bid = blockIdx.x;
  const int gt = bid * 256 + tid, gn = 98 * 256;
  for (int i = gt; i < Bb * Tt * Vv; i += gn) A.xb[i] = (_Float16)A.x[i];
  // h0 -> hbuf slot 31 of each (l,half)
  for (int i = gt; i < 3 * Bb * Hh; i += gn) {
    int l = i >> 16, b = (i >> 9) & 127, col = i & 511;
    int half = b >> 6, bl = b & 63;
    A.hbuf[(size_t)((l * 2 + half) * 32 + 31) * 32768 + bl * 512 + col] = (_Float16)A.h0[i];
  }
  for (int i = gt; i < 3 * 2048; i += gn) {
    int l = i >> 11, cc = i & 2047;
    const float* bi = (l == 0) ? A.bih0 : (l == 1) ? A.bih1 : A.bih2;
    const float* bh = (l == 0) ? A.bhh0 : (l == 1) ? A.bhh1 : A.bhh2;
    A.fbias[i] = bi[cc] + bh[cc];
  }
  for (int i = gt; i < Vv; i += gn) A.fbias[3 * 2048 + i] = A.bfc[i];

  if (bid < 96) {
    const int l = bid >> 5, c = bid & 31;
    _Float16* img = A.wimg + (size_t)bid * 65536;
    const float* Wh = (l == 0) ? A.Whh0 : (l == 1) ? A.Whh1 : A.Whh2;
    for (int e = tid; e < 64 * 512; e += 256) {   // W_hh slice rows r = g*16+jj
      int r = e >> 9, k = e & 511;
      float v = Wh[((r >> 4) * 512 + c * 16 + (r & 15)) * Hh + k];
      img[(r * 512 + k) ^ ((r & 15) << 2)] = (_Float16)v;
    }
    if (l == 0) {
      for (int e = tid; e < 64 * 96; e += 256) {  // W_ih0 [64][112] padded, linear
        int r = e / 96, k = e - r * 96;
        img[32768 + r * 112 + k] = (_Float16)A.Wih0[((r >> 4) * 512 + c * 16 + (r & 15)) * Vv + k];
      }
    } else {
      const float* Wi = (l == 1) ? A.Wih1 : A.Wih2;
      for (int e = tid; e < 64 * 512; e += 256) {
        int r = e >> 9, k = e & 511;
        float v = Wi[((r >> 4) * 512 + c * 16 + (r & 15)) * Hh + k];
        img[32768 + ((r * 512 + k) ^ ((r & 15) << 2))] = (_Float16)v;
      }
    }
  } else {   // bid 96/97: FC image halves
    const int r0 = (bid - 96) * 48;
    for (int e = tid; e < 48 * 512; e += 256) {
      int r = r0 + (e >> 9), k = e & 511;
      A.wfc[(r * 512 + k) ^ ((r & 15) << 2)] = (_Float16)A.Wfc[r * 512 + k];
    }
  }
}

__global__ __launch_bounds__(512, 2) void lstm_persist(KP A) {
  __shared__ _Float16 wlds[65536];   // 128 KB weights
  __shared__ float redx[6144];       // 24 KB: [0..4096) kh-partials, [4096..) gates g,o
  const int tid = threadIdx.x, bid = blockIdx.x;
  const int lane = tid & 63, w = tid >> 6;
  const int l15 = lane & 15, l4 = lane >> 4;
  const int mf = w & 1, nf = (w >> 1) & 1, kh = w >> 2;   // 2x2x2 wave grid
  unsigned* flags = A.flags;

  __builtin_amdgcn_fence(__ATOMIC_ACQUIRE, "agent");

  const bool isfc = (bid >= 192);
  const int l = isfc ? 2 : (bid >> 6);
  const int half = isfc ? (bid - 192) : ((bid >> 5) & 1);
  const int c = isfc ? 0 : (bid & 31);
  const int grp = isfc ? 6 : (l * 2 + half);

  {  // stage pre-swizzled weights once
    const f16x8* src = isfc ? (const f16x8*)A.wfc
                            : (const f16x8*)(A.wimg + (size_t)(l * 32 + c) * 65536);
    f16x8* dst = (f16x8*)wlds;
    const int cnt = isfc ? 6144 : 8192;
    for (int e = tid; e < cnt; e += 512) dst[e] = src[e];
  }

  // wait-set wiring: lane-private (word, target-offset) pairs
  int w1, w2, off1, off2;
  if (!isfc) {
    w1 = grp * 32 + (lane & 31); off1 = 0;                       // own subgroup >= t
    if (lane < 32) {
      if (l > 0) { w2 = (grp - 2) * 32 + lane; off2 = 1; }       // producer >= t+1
      else       { w2 = w1; off2 = 0; }
    } else {
      if (l < 2) { w2 = (grp + 2) * 32 + (lane - 32); off2 = -31; } // consumer guard
      else       { w2 = 6 * 32 + half; off2 = -31; }                // FC guard
    }
  } else {
    w1 = (4 + half) * 32 + (lane & 31); off1 = 1;                // h2(t) ready
    w2 = w1; off2 = 1;
  }

  const int kb = kh * 256;            // k-half base
  const int abase = (mf * 32 + l15) * 512 + kb + (l4 << 2);

  if (!isfc) {
    float biasr[4];
#pragma unroll
    for (int n = 0; n < 4; ++n) biasr[n] = A.fbias[l * 2048 + n * 512 + c * 16 + l15];
    float creg[2][4];
    if (w < 2) {   // kh==0, nf==0 waves own the cell state
#pragma unroll
      for (int m = 0; m < 2; ++m)
#pragma unroll
        for (int q = 0; q < 4; ++q)
          creg[m][q] = A.c0[(size_t)l * 65536 + (half * 64 + mf * 32 + m * 16 + (l4 << 2) + q) * 512 + c * 16 + l15];
    }
    __syncthreads();

    for (int t = 0; t < Tt; ++t) {
      if (tid < 64) wait2(flags, w1, t + off1, w2, t + off2);
      __syncthreads();

      const _Float16* hpv = A.hbuf + (size_t)(grp * 32 + ((t - 1) & 31)) * 32768 + abase;
      f32x4 acc[2][2] = {};
      if (l == 0) {
        f16x4 ah[2][16];
        load2<16>(hpv, ah);                        // issue h loads first
        f16x4 ax[2][3];
#pragma unroll
        for (int m = 0; m < 2; ++m) {
          const _Float16* xp = A.xb + ((size_t)(half * 64 + mf * 32 + m * 16 + l15) * 512 + t) * 96
                               + kh * 48 + (l4 << 2);
#pragma unroll
          for (int i = 0; i < 3; ++i) ax[m][i] = *(const f16x4*)(xp + i * 16);
        }
#pragma unroll
        for (int i = 0; i < 3; ++i)                // x-GEMM (linear [64][112] W_ih0)
#pragma unroll
          for (int n = 0; n < 2; ++n) {
            const int gr = (nf * 2 + n) * 16 + l15;
            f16x4 bv = *(const f16x4*)(wlds + 32768 + gr * 112 + kh * 48 + i * 16 + (l4 << 2));
            acc[0][n] = __builtin_amdgcn_mfma_f32_16x16x16f16(ax[0][i], bv, acc[0][n], 0, 0, 0);
            acc[1][n] = __builtin_amdgcn_mfma_f32_16x16x16f16(ax[1][i], bv, acc[1][n], 0, 0, 0);
          }
        mma2<16, 2>(ah, wlds, kb, nf * 2, l15, l4, acc);
      } else {
        const _Float16* hin = A.hbuf + (size_t)((grp - 2) * 32 + (t & 31)) * 32768 + abase;
        f16x4 ai[2][16], ah[2][16];
        load2<16>(hin, ai);
        load2<16>(hpv, ah);                        // both tiles in flight
        mma2<16, 2>(ai, wlds + 32768, kb, nf * 2, l15, l4, acc);
        mma2<16, 2>(ah, wlds, kb, nf * 2, l15, l4, acc);
      }

      if (kh) {   // publish k-half partials
#pragma unroll
        for (int m = 0; m < 2; ++m)
#pragma unroll
          for (int n = 0; n < 2; ++n)
#pragma unroll
            for (int q = 0; q < 4; ++q)
              redx[((mf * 2 + m) * 4 + nf * 2 + n) * 256 + ((l4 << 2) + q) * 16 + l15] = acc[m][n][q];
      }
      __syncthreads();
      if (!kh) {
#pragma unroll
        for (int m = 0; m < 2; ++m)
#pragma unroll
          for (int n = 0; n < 2; ++n)
#pragma unroll
            for (int q = 0; q < 4; ++q)
              acc[m][n][q] += redx[((mf * 2 + m) * 4 + nf * 2 + n) * 256 + ((l4 << 2) + q) * 16 + l15];
        if (nf) {   // hand gates g,o to the cell waves
#pragma unroll
          for (int m = 0; m < 2; ++m)
#pragma unroll
            for (int n = 0; n < 2; ++n)
#pragma unroll
              for (int q = 0; q < 4; ++q)
                redx[4096 + ((mf * 2 + m) * 2 + n) * 256 + ((l4 << 2) + q) * 16 + l15] = acc[m][n][q];
        }
      }
      __syncthreads();
      if (w < 2) {   // cell update: 32 rows per wave
        _Float16* rp = A.hbuf + (size_t)(grp * 32 + (t & 31)) * 32768;
#pragma unroll
        for (int m = 0; m < 2; ++m)
#pragma unroll
          for (int q = 0; q < 4; ++q) {
            const int bl = mf * 32 + m * 16 + (l4 << 2) + q;
            float gi = acc[m][0][q] + biasr[0];
            float gf = acc[m][1][q] + biasr[1];
            float gg = redx[4096 + ((mf * 2 + m) * 2 + 0) * 256 + ((l4 << 2) + q) * 16 + l15] + biasr[2];
            float go = redx[4096 + ((mf * 2 + m) * 2 + 1) * 256 + ((l4 << 2) + q) * 16 + l15] + biasr[3];
            float iv = sigf(gi), fv = sigf(gf), gv = tanhf(gg), ov = sigf(go);
            float cn = fv * creg[m][q] + iv * gv;
            creg[m][q] = cn;
            float hv = ov * tanhf(cn);
            union { _Float16 h; unsigned short u; } cvt; cvt.h = (_Float16)hv;
            unsigned hb = cvt.u, ob = (unsigned)__shfl_xor((int)hb, 1, 64);
            if ((l15 & 1) == 0)
              st_dc_u32((unsigned*)(rp + bl * 512 + c * 16 + l15), hb | (ob << 16));
            if (t == Tt - 1) {
              A.out[OUT_H + (l * Bb + half * 64 + bl) * 512 + c * 16 + l15] = hv;
              A.out[OUT_C + (l * Bb + half * 64 + bl) * 512 + c * 16 + l15] = cn;
            }
          }
      }
      __syncthreads();   // drains vmcnt: sc1 h-stores at MALL before publish
      if (tid == 0) st_dc_u32(&flags[grp * 32 + c], (unsigned)(t + 1));
    }
  } else {
    float biasr[3];
#pragma unroll
    for (int n = 0; n < 3; ++n) biasr[n] = A.fbias[3 * 2048 + (nf * 3 + n) * 16 + l15];
    __syncthreads();

    for (int t = 0; t < Tt; ++t) {
      if (tid < 64) wait2(flags, w1, t + off1, w2, t + off2);
      __syncthreads();

      const _Float16* hv2 = A.hbuf + (size_t)((4 + half) * 32 + (t & 31)) * 32768 + abase;
      f16x4 a1[2][16];
      load2<16>(hv2, a1);
      f32x4 acc[2][3] = {};
      mma2<16, 3>(a1, wlds, kb, nf * 3, l15, l4, acc);

      if (kh) {
#pragma unroll
        for (int m = 0; m < 2; ++m)
#pragma unroll
          for (int n = 0; n < 3; ++n)
#pragma unroll
            for (int q = 0; q < 4; ++q)
              redx[((mf * 2 + m) * 6 + nf * 3 + n) * 256 + ((l4 << 2) + q) * 16 + l15] = acc[m][n][q];
      }
      __syncthreads();
      if (!kh) {
#pragma unroll
        for (int m = 0; m < 2; ++m)
#pragma unroll
          for (int q = 0; q < 4; ++q) {
            const int b = half * 64 + mf * 32 + m * 16 + (l4 << 2) + q;
#pragma unroll
            for (int n = 0; n < 3; ++n) {
              float v = acc[m][n][q]
                      + redx[((mf * 2 + m) * 6 + nf * 3 + n) * 256 + ((l4 << 2) + q) * 16 + l15];
              A.out[((size_t)b * 512 + t) * 96 + (nf * 3 + n) * 16 + l15] = v + biasr[n];
            }
          }
      }
      __syncthreads();
      if (tid == 0) st_dc_u32(&flags[6 * 32 + half], (unsigned)(t + 1));
    }
  }
}

extern "C" void kernel_launch(void* const* d_in, const int* in_sizes, int n_in,
                              void* d_out, int out_size, void* d_ws, size_t ws_size,
                              hipStream_t stream) {
  char* base = (char*)d_ws;
  KP a;
  a.x    = (const float*)d_in[0];
  a.h0   = (const float*)d_in[1];
  a.c0   = (const float*)d_in[2];
  a.Wih0 = (const float*)d_in[3];  a.Whh0 = (const float*)d_in[4];
  a.bih0 = (const float*)d_in[5];  a.bhh0 = (const float*)d_in[6];
  a.Wih1 = (const float*)d_in[7];  a.Whh1 = (const float*)d_in[8];
  a.bih1 = (const float*)d_in[9];  a.bhh1 = (const float*)d_in[10];
  a.Wih2 = (const float*)d_in[11]; a.Whh2 = (const float*)d_in[12];
  a.bih2 = (const float*)d_in[13]; a.bhh2 = (const float*)d_in[14];
  a.Wfc  = (const float*)d_in[15]; a.bfc  = (const float*)d_in[16];
  a.out  = (float*)d_out;
  a.flags = (unsigned*)base;                     // 1 KB (7 groups x 128B lines)
  a.fbias = (float*)(base + 1024);               // 24,960 B
  a.wimg  = (_Float16*)(base + 26624);           // 12,582,912 B
  a.wfc   = (_Float16*)(base + 12609536);        // 98,304 B
  a.xb    = (_Float16*)(base + 12707840);        // 12,582,912 B
  a.hbuf  = (_Float16*)(base + 25290752);        // 12,582,912 B  (total ~37.9 MB)

  hipError_t err = hipMemsetAsync(a.flags, 0, 1024, stream);
  (void)err;
  hipLaunchKernelGGL(prologue_kernel, dim3(98), dim3(256), 0, stream, a);
  hipLaunchKernelGGL(lstm_persist, dim3(194), dim3(512), 0, stream, a);
}